// Round 6
// baseline (250.684 us; speedup 1.0000x reference)
//
#include <hip/hip_runtime.h>
#include <stdint.h>

// AffineCoupling: B=65536 rows, DIM=128, D_IN=64, HID=512, 2 extra hidden layers.
// Fused bf16-MFMA, 32x32x16 shape. 128 rows/block (512 blocks), 8 waves; each
// wave owns 64 neurons (2 tiles) x 128 rows (4 tiles) = 8 f32x16 accs.
// Per K=16 step: 2 A-frag global loads + 4 B-frag LDS reads feed 8 MFMAs; BOTH
// A and B are fully double-buffered one k-step ahead (frags are 4 VGPRs each,
// total regs ~206 < 256 -> no spill, full LDS/L2 latency cover).
// LDS h layout K-MAJOR TILED: h[row][n] at byte (n>>3)*2048 + row*16 + (n&7)*2.
// All LDS accesses: per-lane base + compile-time immediate; bank-uniform.
// log_s stashed in out's z2 region between s- and t-MLP (same-thread RAW).

#define NROWS 65536
#define RPB   128
#define NBLK  (NROWS / RPB)

// bf16 weight scratch layout (element offsets in d_ws)
#define OFF_S_WIN   0
#define OFF_S_WHID  32768
#define OFF_S_WOUT  557056
#define OFF_T_WIN   589824
#define OFF_T_WHID  622592
#define OFF_T_WOUT  1146880
#define W_ELEMS     1179648

typedef __attribute__((ext_vector_type(8)))  short short8;
typedef __attribute__((ext_vector_type(4)))  float f32x4;
typedef __attribute__((ext_vector_type(16))) float f32x16;

__device__ __forceinline__ uint32_t f2bf1(float f) {
  uint32_t u = __float_as_uint(f);
  return (u + 0x7fffu + ((u >> 16) & 1u)) >> 16;   // RNE
}
__device__ __forceinline__ uint32_t pk2bf(float a, float b) {
  return f2bf1(a) | (f2bf1(b) << 16);
}

// ---------------- weight fp32 -> bf16 prologue ----------------
__global__ void cvt_weights(const float* __restrict__ sWin, const float* __restrict__ sWhid,
                            const float* __restrict__ sWout, const float* __restrict__ tWin,
                            const float* __restrict__ tWhid, const float* __restrict__ tWout,
                            uint16_t* __restrict__ wbf) {
  int g = blockIdx.x * blockDim.x + threadIdx.x;
  int e = g * 4;
  if (e >= W_ELEMS) return;
  const float* src; int off;
  if      (e < OFF_S_WHID) { src = sWin;  off = e; }
  else if (e < OFF_S_WOUT) { src = sWhid; off = e - OFF_S_WHID; }
  else if (e < OFF_T_WIN)  { src = sWout; off = e - OFF_S_WOUT; }
  else if (e < OFF_T_WHID) { src = tWin;  off = e - OFF_T_WIN; }
  else if (e < OFF_T_WOUT) { src = tWhid; off = e - OFF_T_WHID; }
  else                     { src = tWout; off = e - OFF_T_WOUT; }
  f32x4 v = *(const f32x4*)(src + off);
  uint2 r; r.x = pk2bf(v.x, v.y); r.y = pk2bf(v.z, v.w);
  *(uint2*)(wbf + e) = r;
}

// ---------------- fragment loaders ----------------
// A-frag (weights, row-major [M][K]), 32x32x16: lane l supplies
// W[m = base + (l&31)][k = (l>>5)*8 + j], j=0..7 -> 16B load at element idx.
template<bool BF>
__device__ __forceinline__ short8 ldW(const uint16_t* __restrict__ wb,
                                      const float* __restrict__ wf, int idx) {
  if (BF) {
    return *(const short8*)(wb + idx);
  } else {  // fallback: convert fp32 weights on the fly
    f32x4 x = *(const f32x4*)(wf + idx);
    f32x4 y = *(const f32x4*)(wf + idx + 4);
    short8 r;
    r[0] = (short)f2bf1(x.x); r[1] = (short)f2bf1(x.y);
    r[2] = (short)f2bf1(x.z); r[3] = (short)f2bf1(x.w);
    r[4] = (short)f2bf1(y.x); r[5] = (short)f2bf1(y.y);
    r[6] = (short)f2bf1(y.z); r[7] = (short)f2bf1(y.w);
    return r;
  }
}

// ---------------- epilogue: bias + relu + pack + k-major LDS store ----------------
// C layout (32x32): col = lane&31 = batch row; m = (reg&3) + 8*(reg>>2) + 4*(lane>>5).
// reg quad q holds 4 consecutive neurons m0 = 8q + 4*(lane>>5).
// Store byte = (8*wave + 4*nt + q)*2048 + (rt*32 + l31)*16 + (lane>>5)*8.
__device__ __forceinline__ void store_h32(f32x16 acc[8], const float* __restrict__ bias,
                                          uint16_t* hdst, int wave, int lane) {
  const int l31 = lane & 31, lh = lane >> 5;
  __syncthreads();   // all waves done READING h (h is read+written in place)
  char* wp = (char*)hdst + wave * 16384 + l31 * 16 + lh * 8;
  #pragma unroll
  for (int nt = 0; nt < 2; ++nt) {
    #pragma unroll
    for (int q = 0; q < 4; ++q) {
      const int m0 = wave * 64 + nt * 32 + q * 8 + lh * 4;
      f32x4 bv = *(const f32x4*)(bias + m0);
      #pragma unroll
      for (int rt = 0; rt < 4; ++rt) {
        float v0 = acc[nt * 4 + rt][q * 4 + 0] + bv.x;
        float v1 = acc[nt * 4 + rt][q * 4 + 1] + bv.y;
        float v2 = acc[nt * 4 + rt][q * 4 + 2] + bv.z;
        float v3 = acc[nt * 4 + rt][q * 4 + 3] + bv.w;
        uint2 p;
        p.x = pk2bf(fmaxf(v0, 0.f), fmaxf(v1, 0.f));
        p.y = pk2bf(fmaxf(v2, 0.f), fmaxf(v3, 0.f));
        *(uint2*)(wp + nt * 8192 + q * 2048 + rt * 512) = p;
      }
    }
  }
  __syncthreads();
}

// ---------------- layer 1: h = relu(W @ z1^T + b), K=64, B built from global z ----------------
template<bool BF>
__device__ __forceinline__ void dense_in(
    const uint16_t* __restrict__ wb, const float* __restrict__ wf,
    const float* __restrict__ bias, const float* __restrict__ z, long rowbase,
    uint16_t* hdst, int wave, int lane) {
  const int l31 = lane & 31, lh = lane >> 5;
  f32x16 acc[8];
  #pragma unroll
  for (int i = 0; i < 8; ++i) acc[i] = (f32x16)0.f;
  const int wrow = (64 * wave + l31) * 64 + 8 * lh;   // nt tile stride = 32*64 = 2048 elems
  #pragma unroll
  for (int ks = 0; ks < 4; ++ks) {
    short8 a[2];
    #pragma unroll
    for (int nt = 0; nt < 2; ++nt) a[nt] = ldW<BF>(wb, wf, wrow + nt * 2048 + ks * 16);
    #pragma unroll
    for (int rt = 0; rt < 4; ++rt) {
      const float* zp = z + (rowbase + rt * 32 + l31) * 128 + ks * 16 + 8 * lh;
      f32x4 u = *(const f32x4*)zp;
      f32x4 v = *(const f32x4*)(zp + 4);
      short8 b;
      b[0] = (short)f2bf1(u.x); b[1] = (short)f2bf1(u.y);
      b[2] = (short)f2bf1(u.z); b[3] = (short)f2bf1(u.w);
      b[4] = (short)f2bf1(v.x); b[5] = (short)f2bf1(v.y);
      b[6] = (short)f2bf1(v.z); b[7] = (short)f2bf1(v.w);
      #pragma unroll
      for (int nt = 0; nt < 2; ++nt)
        acc[nt * 4 + rt] = __builtin_amdgcn_mfma_f32_32x32x16_bf16(a[nt], b, acc[nt * 4 + rt], 0, 0, 0);
    }
  }
  store_h32(acc, bias, hdst, wave, lane);
}

// ---------------- hidden layer: h = relu(W @ h^T + b), K=512 ----------------
// 32 K=16 steps; A (2 frags) and B (4 frags) fully double-buffered one step
// ahead (explicit 2-step body -> all frag indices static). B byte address:
// base(lh*2048 + l31*16) + ks*4096 + rt*512, chunked 8 steps per bb bump.
template<bool BF>
__device__ __forceinline__ void dense_relu512(
    const uint16_t* __restrict__ wb, const float* __restrict__ wf,
    const float* __restrict__ bias, uint16_t* hbuf, int wave, int lane) {
  const int l31 = lane & 31, lh = lane >> 5;
  f32x16 acc[8];
  #pragma unroll
  for (int i = 0; i < 8; ++i) acc[i] = (f32x16)0.f;
  const int wrow = (64 * wave + l31) * 512 + 8 * lh;  // nt tile stride = 32*512 = 16384
  const char* bb = (const char*)hbuf + lh * 2048 + l31 * 16;

  short8 aA[2], aB[2], bA[4], bB[4];
  #pragma unroll
  for (int nt = 0; nt < 2; ++nt) aA[nt] = ldW<BF>(wb, wf, wrow + nt * 16384);
  #pragma unroll
  for (int rt = 0; rt < 4; ++rt) bA[rt] = *(const short8*)(bb + rt * 512);

  #pragma unroll 1
  for (int chunk = 0; chunk < 4; ++chunk) {
    const int kbase = chunk * 128;                     // element k at chunk start
    #pragma unroll
    for (int p = 0; p < 4; ++p) {
      // ---- step s = chunk*8 + 2p: prefetch s+1 into B-buffers, compute A-buffers
      {
        const int kn = kbase + p * 32 + 16;            // k of step s+1 (<=496 always)
        #pragma unroll
        for (int nt = 0; nt < 2; ++nt) aB[nt] = ldW<BF>(wb, wf, wrow + nt * 16384 + kn);
        #pragma unroll
        for (int rt = 0; rt < 4; ++rt)
          bB[rt] = *(const short8*)(bb + (p * 2 + 1) * 4096 + rt * 512);
        __builtin_amdgcn_s_setprio(1);
        #pragma unroll
        for (int nt = 0; nt < 2; ++nt)
          #pragma unroll
          for (int rt = 0; rt < 4; ++rt)
            acc[nt * 4 + rt] = __builtin_amdgcn_mfma_f32_32x32x16_bf16(aA[nt], bA[rt], acc[nt * 4 + rt], 0, 0, 0);
        __builtin_amdgcn_s_setprio(0);
      }
      // ---- step s+1: prefetch s+2 into A-buffers, compute B-buffers
      {
        int kn = kbase + p * 32 + 32;                  // k of step s+2
        if (kn > 496) kn = 496;                        // clamp (re-read; harmless)
        #pragma unroll
        for (int nt = 0; nt < 2; ++nt) aA[nt] = ldW<BF>(wb, wf, wrow + nt * 16384 + kn);
        #pragma unroll
        for (int rt = 0; rt < 4; ++rt)
          bA[rt] = *(const short8*)(bb + (p * 2 + 2) * 4096 + rt * 512);   // p=3 -> next chunk/guard
        __builtin_amdgcn_s_setprio(1);
        #pragma unroll
        for (int nt = 0; nt < 2; ++nt)
          #pragma unroll
          for (int rt = 0; rt < 4; ++rt)
            acc[nt * 4 + rt] = __builtin_amdgcn_mfma_f32_32x32x16_bf16(aB[nt], bB[rt], acc[nt * 4 + rt], 0, 0, 0);
        __builtin_amdgcn_s_setprio(0);
      }
    }
    bb += 32768;
  }
  store_h32(acc, bias, hbuf, wave, lane);
}

// ---------------- output layer: 64 neurons x 32 rows per wave, waves 0..3 ----------------
template<bool BF>
__device__ __forceinline__ void final_layer(
    const uint16_t* __restrict__ wb, const float* __restrict__ wf,
    const uint16_t* hbuf, int wave, int lane, f32x16 acc[2]) {
  const int l31 = lane & 31, lh = lane >> 5;
  acc[0] = (f32x16)0.f; acc[1] = (f32x16)0.f;
  const int wrow = l31 * 512 + 8 * lh;                 // Wout: nt tile stride 16384
  const char* fb = (const char*)hbuf + lh * 2048 + l31 * 16 + wave * 512;  // rows wave*32..+31
  #pragma unroll 1
  for (int chunk = 0; chunk < 4; ++chunk) {
    #pragma unroll
    for (int p = 0; p < 8; ++p) {
      const int k = chunk * 128 + p * 16;
      short8 b = *(const short8*)(fb + p * 4096);
      #pragma unroll
      for (int nt = 0; nt < 2; ++nt) {
        short8 a = ldW<BF>(wb, wf, wrow + nt * 16384 + k);
        acc[nt] = __builtin_amdgcn_mfma_f32_32x32x16_bf16(a, b, acc[nt], 0, 0, 0);
      }
    }
    fb += 32768;
  }
}

// ---------------- fused coupling kernel: 128 rows/block, 8 waves ----------------
template<bool BF>
__global__ __launch_bounds__(512, 2) void coupling(
    const float* __restrict__ z,
    const float* __restrict__ sWin, const float* __restrict__ sbin,
    const float* __restrict__ sWhid, const float* __restrict__ sbhid,
    const float* __restrict__ sWout, const float* __restrict__ sbout,
    const float* __restrict__ tWin, const float* __restrict__ tbin,
    const float* __restrict__ tWhid, const float* __restrict__ tbhid,
    const float* __restrict__ tWout, const float* __restrict__ tbout,
    const uint16_t* __restrict__ wbf, float* __restrict__ out) {
  extern __shared__ __align__(16) uint16_t h[];     // 128 KiB k-major + 8 KiB guard
  const int tid = threadIdx.x;
  const int wave = tid >> 6, lane = tid & 63;
  const int l31 = lane & 31, lh = lane >> 5;
  const long rowbase = (long)blockIdx.x * RPB;

  // ---------------- s MLP ----------------
  dense_in<BF>(wbf + OFF_S_WIN, sWin, sbin, z, rowbase, h, wave, lane);
  dense_relu512<BF>(wbf + OFF_S_WHID, sWhid, sbhid, h, wave, lane);
  dense_relu512<BF>(wbf + OFF_S_WHID + 262144, sWhid + 262144, sbhid + 512, h, wave, lane);

  if (wave < 4) {
    f32x16 acc[2];
    final_layer<BF>(wbf + OFF_S_WOUT, sWout, h, wave, lane, acc);
    const long row = rowbase + wave * 32 + l31;
    float sum = 0.f;
    #pragma unroll
    for (int nt = 0; nt < 2; ++nt) {
      #pragma unroll
      for (int q = 0; q < 4; ++q) {
        const int m0 = nt * 32 + q * 8 + lh * 4;
        f32x4 bv = *(const f32x4*)(sbout + m0);
        f32x4 v;
        v.x = fminf(fmaxf(acc[nt][q * 4 + 0] + bv.x, -2.f), 2.f);
        v.y = fminf(fmaxf(acc[nt][q * 4 + 1] + bv.y, -2.f), 2.f);
        v.z = fminf(fmaxf(acc[nt][q * 4 + 2] + bv.z, -2.f), 2.f);
        v.w = fminf(fmaxf(acc[nt][q * 4 + 3] + bv.w, -2.f), 2.f);
        sum += v.x + v.y + v.z + v.w;
        *(f32x4*)(out + row * 128 + 64 + m0) = v;     // stash log_s
      }
    }
    sum += __shfl_xor(sum, 32, 64);                   // lanes l and l+32 share a row
    if (lane < 32) out[(long)NROWS * 128 + row] = sum;  // log_det
  } else {
    // waves 4..7: copy z1 passthrough (exact fp32), 128 rows x 64 cols
    #pragma unroll
    for (int i = 0; i < 8; ++i) {
      int v = (wave - 4) * 64 + lane + i * 256;
      int row = v >> 4, kc = (v & 15) * 4;
      *(f32x4*)(out + (rowbase + row) * 128 + kc) =
          *(const f32x4*)(z + (rowbase + row) * 128 + kc);
    }
  }
  __syncthreads();

  // ---------------- t MLP ----------------
  dense_in<BF>(wbf + OFF_T_WIN, tWin, tbin, z, rowbase, h, wave, lane);
  dense_relu512<BF>(wbf + OFF_T_WHID, tWhid, tbhid, h, wave, lane);
  dense_relu512<BF>(wbf + OFF_T_WHID + 262144, tWhid + 262144, tbhid + 512, h, wave, lane);

  if (wave < 4) {
    f32x16 acc[2];
    final_layer<BF>(wbf + OFF_T_WOUT, tWout, h, wave, lane, acc);
    const long row = rowbase + wave * 32 + l31;
    #pragma unroll
    for (int nt = 0; nt < 2; ++nt) {
      #pragma unroll
      for (int q = 0; q < 4; ++q) {
        const int m0 = nt * 32 + q * 8 + lh * 4;
        f32x4 bv = *(const f32x4*)(tbout + m0);
        f32x4 tv;
        tv.x = acc[nt][q * 4 + 0] + bv.x;
        tv.y = acc[nt][q * 4 + 1] + bv.y;
        tv.z = acc[nt][q * 4 + 2] + bv.z;
        tv.w = acc[nt][q * 4 + 3] + bv.w;
        const long o = row * 128 + 64 + m0;
        f32x4 ls = *(const f32x4*)(out + o);   // log_s stashed by s-phase (same thread)
        f32x4 z2 = *(const f32x4*)(z + o);     // z2 = z[:,64:] (same offsets)
        f32x4 r;
        r.x = z2.x * __expf(ls.x) + tv.x;
        r.y = z2.y * __expf(ls.y) + tv.y;
        r.z = z2.z * __expf(ls.z) + tv.z;
        r.w = z2.w * __expf(ls.w) + tv.w;
        *(f32x4*)(out + o) = r;
      }
    }
  }
}

extern "C" void kernel_launch(void* const* d_in, const int* in_sizes, int n_in,
                              void* d_out, int out_size, void* d_ws, size_t ws_size,
                              hipStream_t stream) {
  const float* z     = (const float*)d_in[0];
  const float* sWin  = (const float*)d_in[1];
  const float* sbin  = (const float*)d_in[2];
  const float* sWhid = (const float*)d_in[3];
  const float* sbhid = (const float*)d_in[4];
  const float* sWout = (const float*)d_in[5];
  const float* sbout = (const float*)d_in[6];
  const float* tWin  = (const float*)d_in[7];
  const float* tbin  = (const float*)d_in[8];
  const float* tWhid = (const float*)d_in[9];
  const float* tbhid = (const float*)d_in[10];
  const float* tWout = (const float*)d_in[11];
  const float* tbout = (const float*)d_in[12];
  float* out = (float*)d_out;
  const size_t lds_bytes = 139264;   // 128 KiB h (k-major) + 8 KiB prefetch guard

  if (ws_size >= (size_t)W_ELEMS * sizeof(uint16_t)) {
    uint16_t* wbf = (uint16_t*)d_ws;
    cvt_weights<<<W_ELEMS / 4 / 256, 256, 0, stream>>>(sWin, sWhid, sWout, tWin, tWhid, tWout, wbf);
    coupling<true><<<NBLK, 512, lds_bytes, stream>>>(z, sWin, sbin, sWhid, sbhid, sWout, sbout,
                                                     tWin, tbin, tWhid, tbhid, tWout, tbout, wbf, out);
  } else {
    coupling<false><<<NBLK, 512, lds_bytes, stream>>>(z, sWin, sbin, sWhid, sbhid, sWout, sbout,
                                                      tWin, tbin, tWhid, tbhid, tWout, tbout,
                                                      (const uint16_t*)d_in[1], out);
  }
}

// Round 7
// 224.767 us; speedup vs baseline: 1.1153x; 1.1153x over previous
//
#include <hip/hip_runtime.h>
#include <stdint.h>

// AffineCoupling: B=65536 rows, DIM=128, D_IN=64, HID=512, 2 extra hidden layers.
// Fused bf16-MFMA, 32x32x16. 64 rows/block (1024 blocks), 8 waves, 2 blocks/CU
// (68KB LDS, launch_bounds(512,4) -> 4 waves/SIMD TLP).
// Wave owns 64 neurons (nt=2) x 64 rows (rt=2): per K=16 step 2 A + 2 B loads
// feed 4 MFMAs; both operands double-buffered one step ahead.
// WEIGHTS REPACKED k-major-tiled in d_ws: elem(m,k) -> (m>>5)*(32K) + (k>>3)*256
// + (m&31)*8 + (k&7), so an A-frag is ONE CONTIGUOUS 1KB wave-load (16 cache
// lines, not 64 scattered) -- removes the TCP request-rate bottleneck that
// pinned MfmaUtil at ~25% across R3-R6.
// LDS h layout K-MAJOR TILED: h[row][n] at byte (n>>3)*1024 + row*16 + (n&7)*2.
// Final (64-neuron) layers: k-split across 8 waves + LDS partial reduce.
// log_s stashed in out's z2 region between s- and t-MLP (same-thread RAW).

#define NROWS 65536
#define RPB   64
#define NBLK  (NROWS / RPB)

// bf16 weight scratch layout (element offsets in d_ws)
#define OFF_S_WIN   0
#define OFF_S_WHID  32768
#define OFF_S_WOUT  557056
#define OFF_T_WIN   589824
#define OFF_T_WHID  622592
#define OFF_T_WOUT  1146880
#define W_ELEMS     1179648

// LDS byte offsets (within per-block dynamic LDS, 69632 B total)
#define P_SCR  0        // final-layer partial tiles: 4 x 4352 B (reuses dead h)
#define SC2    17408    // log_det col-half sums: 128 x 4 B

typedef __attribute__((ext_vector_type(8)))  short short8;
typedef __attribute__((ext_vector_type(4)))  float f32x4;
typedef __attribute__((ext_vector_type(16))) float f32x16;

__device__ __forceinline__ uint32_t f2bf1(float f) {
  uint32_t u = __float_as_uint(f);
  return (u + 0x7fffu + ((u >> 16) & 1u)) >> 16;   // RNE
}
__device__ __forceinline__ uint32_t pk2bf(float a, float b) {
  return f2bf1(a) | (f2bf1(b) << 16);
}

// ---------------- weight fp32 -> bf16 + k-major repack prologue ----------------
__global__ void cvt_weights(const float* __restrict__ sWin, const float* __restrict__ sWhid,
                            const float* __restrict__ sWout, const float* __restrict__ tWin,
                            const float* __restrict__ tWhid, const float* __restrict__ tWout,
                            uint16_t* __restrict__ wbf) {
  int g = blockIdx.x * blockDim.x + threadIdx.x;
  int e = g * 4;
  if (e >= W_ELEMS) return;
  const float* src; int off, base; bool k64;
  if      (e < OFF_S_WHID) { src = sWin;  off = e;              base = OFF_S_WIN;  k64 = true; }
  else if (e < OFF_S_WOUT) { src = sWhid; off = e - OFF_S_WHID; base = OFF_S_WHID; k64 = false; }
  else if (e < OFF_T_WIN)  { src = sWout; off = e - OFF_S_WOUT; base = OFF_S_WOUT; k64 = false; }
  else if (e < OFF_T_WHID) { src = tWin;  off = e - OFF_T_WIN;  base = OFF_T_WIN;  k64 = true; }
  else if (e < OFF_T_WOUT) { src = tWhid; off = e - OFF_T_WHID; base = OFF_T_WHID; k64 = false; }
  else                     { src = tWout; off = e - OFF_T_WOUT; base = OFF_T_WOUT; k64 = false; }
  int m, k, tsz;
  if (k64) { m = off >> 6; k = off & 63;  tsz = 2048;  }
  else     { m = off >> 9; k = off & 511; tsz = 16384; }
  int dest = base + (m >> 5) * tsz + (k >> 3) * 256 + (m & 31) * 8 + (k & 7);
  f32x4 v = *(const f32x4*)(src + off);
  uint2 r; r.x = pk2bf(v.x, v.y); r.y = pk2bf(v.z, v.w);
  *(uint2*)(wbf + dest) = r;
}

// ---------------- A-frag loader ----------------
// packed idx = contiguous 1KB wave-load; orig idx used only by the BF=false fallback.
template<bool BF>
__device__ __forceinline__ short8 ldW(const uint16_t* __restrict__ wb,
                                      const float* __restrict__ wf, int pidx, int oidx) {
  if (BF) {
    return *(const short8*)(wb + pidx);
  } else {
    f32x4 x = *(const f32x4*)(wf + oidx);
    f32x4 y = *(const f32x4*)(wf + oidx + 4);
    short8 r;
    r[0] = (short)f2bf1(x.x); r[1] = (short)f2bf1(x.y);
    r[2] = (short)f2bf1(x.z); r[3] = (short)f2bf1(x.w);
    r[4] = (short)f2bf1(y.x); r[5] = (short)f2bf1(y.y);
    r[6] = (short)f2bf1(y.z); r[7] = (short)f2bf1(y.w);
    return r;
  }
}

// ---------------- epilogue: bias + relu + pack + k-major LDS store ----------------
// C layout (32x32): col=lane&31=batch row; m=(reg&3)+8*(reg>>2)+4*(lane>>5).
__device__ __forceinline__ void store_h32(f32x16 acc[2][2], const float* __restrict__ bias,
                                          uint16_t* hdst, int wave, int lane) {
  const int l31 = lane & 31, lh = lane >> 5;
  __syncthreads();   // all waves done READING h (h is read+written in place)
  char* wp = (char*)hdst + wave * 8192 + l31 * 16 + lh * 8;
  #pragma unroll
  for (int nt = 0; nt < 2; ++nt) {
    #pragma unroll
    for (int q = 0; q < 4; ++q) {
      const int m0 = wave * 64 + nt * 32 + q * 8 + lh * 4;
      f32x4 bv = *(const f32x4*)(bias + m0);
      #pragma unroll
      for (int rt = 0; rt < 2; ++rt) {
        float v0 = acc[nt][rt][q * 4 + 0] + bv.x;
        float v1 = acc[nt][rt][q * 4 + 1] + bv.y;
        float v2 = acc[nt][rt][q * 4 + 2] + bv.z;
        float v3 = acc[nt][rt][q * 4 + 3] + bv.w;
        uint2 p;
        p.x = pk2bf(fmaxf(v0, 0.f), fmaxf(v1, 0.f));
        p.y = pk2bf(fmaxf(v2, 0.f), fmaxf(v3, 0.f));
        *(uint2*)(wp + nt * 4096 + q * 1024 + rt * 512) = p;
      }
    }
  }
  __syncthreads();
}

// ---------------- layer 1: h = relu(W @ z1^T + b), K=64, B built from global z ----------------
template<bool BF>
__device__ __forceinline__ void dense_in(
    const uint16_t* __restrict__ wb, const float* __restrict__ wf,
    const float* __restrict__ bias, const float* __restrict__ z, long rowbase,
    uint16_t* hdst, int wave, int lane) {
  const int l31 = lane & 31, lh = lane >> 5;
  f32x16 acc[2][2];
  #pragma unroll
  for (int i = 0; i < 2; ++i)
    #pragma unroll
    for (int j = 0; j < 2; ++j) acc[i][j] = (f32x16)0.f;
  #pragma unroll
  for (int ks = 0; ks < 4; ++ks) {
    short8 a[2];
    #pragma unroll
    for (int nt = 0; nt < 2; ++nt)
      a[nt] = ldW<BF>(wb, wf,
                      (wave * 2 + nt) * 2048 + (2 * ks + lh) * 256 + l31 * 8,
                      (wave * 64 + nt * 32 + l31) * 64 + ks * 16 + lh * 8);
    #pragma unroll
    for (int rt = 0; rt < 2; ++rt) {
      const float* zp = z + (rowbase + rt * 32 + l31) * 128 + ks * 16 + lh * 8;
      f32x4 u = *(const f32x4*)zp;
      f32x4 v = *(const f32x4*)(zp + 4);
      short8 b;
      b[0] = (short)f2bf1(u.x); b[1] = (short)f2bf1(u.y);
      b[2] = (short)f2bf1(u.z); b[3] = (short)f2bf1(u.w);
      b[4] = (short)f2bf1(v.x); b[5] = (short)f2bf1(v.y);
      b[6] = (short)f2bf1(v.z); b[7] = (short)f2bf1(v.w);
      #pragma unroll
      for (int nt = 0; nt < 2; ++nt)
        acc[nt][rt] = __builtin_amdgcn_mfma_f32_32x32x16_bf16(a[nt], b, acc[nt][rt], 0, 0, 0);
    }
  }
  store_h32(acc, bias, hdst, wave, lane);
}

// ---------------- hidden layer: h = relu(W @ h^T + b), K=512 ----------------
// 32 K=16 steps; A and B double-buffered one step ahead (static names).
template<bool BF>
__device__ __forceinline__ void dense_relu512(
    const uint16_t* __restrict__ wb, const float* __restrict__ wf,
    const float* __restrict__ bias, uint16_t* hbuf, int wave, int lane) {
  const int l31 = lane & 31, lh = lane >> 5;
  f32x16 acc[2][2];
  #pragma unroll
  for (int i = 0; i < 2; ++i)
    #pragma unroll
    for (int j = 0; j < 2; ++j) acc[i][j] = (f32x16)0.f;
  const int wbaseP = wave * 2 * 16384 + lh * 256 + l31 * 8;   // + nt*16384 + ks*512
  const int wbaseO = (wave * 64 + l31) * 512 + lh * 8;        // + nt*32*512 + ks*16
  const char* bb = (const char*)hbuf + l31 * 16 + lh * 1024;  // + ks*2048 + rt*512

  short8 aA[2], aB[2], bA[2], bB[2];
  #pragma unroll
  for (int nt = 0; nt < 2; ++nt)
    aA[nt] = ldW<BF>(wb, wf, wbaseP + nt * 16384, wbaseO + nt * 16384);
  #pragma unroll
  for (int rt = 0; rt < 2; ++rt) bA[rt] = *(const short8*)(bb + rt * 512);

  #pragma unroll
  for (int ks = 0; ks < 32; ks += 2) {
    // step ks: compute A-buffers, prefetch ks+1 into B-buffers
    #pragma unroll
    for (int nt = 0; nt < 2; ++nt)
      aB[nt] = ldW<BF>(wb, wf, wbaseP + nt * 16384 + (ks + 1) * 512,
                               wbaseO + nt * 16384 + (ks + 1) * 16);
    #pragma unroll
    for (int rt = 0; rt < 2; ++rt)
      bB[rt] = *(const short8*)(bb + (ks + 1) * 2048 + rt * 512);
    __builtin_amdgcn_s_setprio(1);
    #pragma unroll
    for (int nt = 0; nt < 2; ++nt)
      #pragma unroll
      for (int rt = 0; rt < 2; ++rt)
        acc[nt][rt] = __builtin_amdgcn_mfma_f32_32x32x16_bf16(aA[nt], bA[rt], acc[nt][rt], 0, 0, 0);
    __builtin_amdgcn_s_setprio(0);
    // step ks+1: prefetch ks+2 into A-buffers (clamped at tail; B guard read ok)
    const int kp = (ks + 2 > 31) ? 31 : ks + 2;
    #pragma unroll
    for (int nt = 0; nt < 2; ++nt)
      aA[nt] = ldW<BF>(wb, wf, wbaseP + nt * 16384 + kp * 512,
                               wbaseO + nt * 16384 + kp * 16);
    #pragma unroll
    for (int rt = 0; rt < 2; ++rt)
      bA[rt] = *(const short8*)(bb + (ks + 2) * 2048 + rt * 512);  // ks=30 tail: guard region
    __builtin_amdgcn_s_setprio(1);
    #pragma unroll
    for (int nt = 0; nt < 2; ++nt)
      #pragma unroll
      for (int rt = 0; rt < 2; ++rt)
        acc[nt][rt] = __builtin_amdgcn_mfma_f32_32x32x16_bf16(aB[nt], bB[rt], acc[nt][rt], 0, 0, 0);
    __builtin_amdgcn_s_setprio(0);
  }
  store_h32(acc, bias, hbuf, wave, lane);
}

// ---------------- final layer partial: 64 neurons, k-split across 8 waves ----------------
// wave w: nt=w&1 (32 neurons), rt=(w>>1)&1 (32 rows), kh=w>>2 (k half).
template<bool BF>
__device__ __forceinline__ void final_partial(
    const uint16_t* __restrict__ wb, const float* __restrict__ wf,
    const uint16_t* hbuf, int nt, int rt, int kh, int lane, f32x16& acc) {
  const int l31 = lane & 31, lh = lane >> 5;
  acc = (f32x16)0.f;
  #pragma unroll
  for (int ks = 0; ks < 16; ++ks) {
    const int kt = 2 * (kh * 16 + ks) + lh;
    short8 a = ldW<BF>(wb, wf, nt * 16384 + kt * 256 + l31 * 8,
                       (nt * 32 + l31) * 512 + kh * 256 + ks * 16 + lh * 8);
    short8 b = *(const short8*)((const char*)hbuf + kt * 1024 + (rt * 32 + l31) * 16);
    acc = __builtin_amdgcn_mfma_f32_32x32x16_bf16(a, b, acc, 0, 0, 0);
  }
}

// ---------------- fused coupling kernel: 64 rows/block, 8 waves, 2 blocks/CU ----------------
template<bool BF>
__global__ __launch_bounds__(512, 4) void coupling(
    const float* __restrict__ z,
    const float* __restrict__ sWin, const float* __restrict__ sbin,
    const float* __restrict__ sWhid, const float* __restrict__ sbhid,
    const float* __restrict__ sWout, const float* __restrict__ sbout,
    const float* __restrict__ tWin, const float* __restrict__ tbin,
    const float* __restrict__ tWhid, const float* __restrict__ tbhid,
    const float* __restrict__ tWout, const float* __restrict__ tbout,
    const uint16_t* __restrict__ wbf, float* __restrict__ out) {
  extern __shared__ __align__(16) uint16_t h[];     // 64KB k-major h + guard
  const int tid = threadIdx.x;
  const int wave = tid >> 6, lane = tid & 63;
  const int l31 = lane & 31, lh = lane >> 5;
  const long rowbase = (long)blockIdx.x * RPB;
  const int fnt = wave & 1, frt = (wave >> 1) & 1, fkh = wave >> 2;

  // ---------------- s MLP ----------------
  dense_in<BF>(wbf + OFF_S_WIN, sWin, sbin, z, rowbase, h, wave, lane);
  dense_relu512<BF>(wbf + OFF_S_WHID, sWhid, sbhid, h, wave, lane);
  dense_relu512<BF>(wbf + OFF_S_WHID + 262144, sWhid + 262144, sbhid + 512, h, wave, lane);

  // z1 passthrough copy (all waves; independent of h)
  #pragma unroll
  for (int i = 0; i < 2; ++i) {
    int v = tid + i * 512;
    int row = v >> 4, kc = (v & 15) * 4;
    *(f32x4*)(out + (rowbase + row) * 128 + kc) =
        *(const f32x4*)(z + (rowbase + row) * 128 + kc);
  }

  // ---- s final: k-split partials + LDS reduce + clip/stash/logdet ----
  {
    f32x16 fa;
    final_partial<BF>(wbf + OFF_S_WOUT, sWout, h, fnt, frt, fkh, lane, fa);
    __syncthreads();                 // all reads of h done; scratch area now reusable
    char* sc = (char*)h + P_SCR + (fnt * 2 + frt) * 4352 + lane * 68;
    if (fkh) {
      #pragma unroll
      for (int q = 0; q < 4; ++q)
        *(f32x4*)(sc + q * 16) = (f32x4){fa[q * 4], fa[q * 4 + 1], fa[q * 4 + 2], fa[q * 4 + 3]};
    }
    __syncthreads();
    if (!fkh) {
      const long row = rowbase + frt * 32 + l31;
      float sum = 0.f;
      #pragma unroll
      for (int q = 0; q < 4; ++q) {
        f32x4 p = *(const f32x4*)(sc + q * 16);
        const int m0 = fnt * 32 + q * 8 + lh * 4;
        f32x4 bv = *(const f32x4*)(sbout + m0);
        f32x4 v;
        v.x = fminf(fmaxf(fa[q * 4 + 0] + p.x + bv.x, -2.f), 2.f);
        v.y = fminf(fmaxf(fa[q * 4 + 1] + p.y + bv.y, -2.f), 2.f);
        v.z = fminf(fmaxf(fa[q * 4 + 2] + p.z + bv.z, -2.f), 2.f);
        v.w = fminf(fmaxf(fa[q * 4 + 3] + p.w + bv.w, -2.f), 2.f);
        sum += v.x + v.y + v.z + v.w;
        *(f32x4*)(out + row * 128 + 64 + m0) = v;   // stash log_s
      }
      sum += __shfl_xor(sum, 32, 64);               // combine lh col-halves
      if (lane < 32)
        *(float*)((char*)h + SC2 + (fnt * 64 + frt * 32 + l31) * 4) = sum;
    }
    __syncthreads();
    if ((wave == 0 || wave == 2) && lane < 32) {    // nt=0, kh=0 waves finish log_det
      float t0 = *(const float*)((char*)h + SC2 + (frt * 32 + l31) * 4);
      float t1 = *(const float*)((char*)h + SC2 + (64 + frt * 32 + l31) * 4);
      out[(long)NROWS * 128 + rowbase + frt * 32 + l31] = t0 + t1;
    }
  }
  __syncthreads();

  // ---------------- t MLP ----------------
  dense_in<BF>(wbf + OFF_T_WIN, tWin, tbin, z, rowbase, h, wave, lane);
  dense_relu512<BF>(wbf + OFF_T_WHID, tWhid, tbhid, h, wave, lane);
  dense_relu512<BF>(wbf + OFF_T_WHID + 262144, tWhid + 262144, tbhid + 512, h, wave, lane);

  // ---- t final: k-split partials + LDS reduce + z2 combine ----
  {
    f32x16 fa;
    final_partial<BF>(wbf + OFF_T_WOUT, tWout, h, fnt, frt, fkh, lane, fa);
    __syncthreads();
    char* sc = (char*)h + P_SCR + (fnt * 2 + frt) * 4352 + lane * 68;
    if (fkh) {
      #pragma unroll
      for (int q = 0; q < 4; ++q)
        *(f32x4*)(sc + q * 16) = (f32x4){fa[q * 4], fa[q * 4 + 1], fa[q * 4 + 2], fa[q * 4 + 3]};
    }
    __syncthreads();
    if (!fkh) {
      const long row = rowbase + frt * 32 + l31;
      #pragma unroll
      for (int q = 0; q < 4; ++q) {
        f32x4 p = *(const f32x4*)(sc + q * 16);
        const int m0 = fnt * 32 + q * 8 + lh * 4;
        f32x4 bv = *(const f32x4*)(tbout + m0);
        f32x4 tv;
        tv.x = fa[q * 4 + 0] + p.x + bv.x;
        tv.y = fa[q * 4 + 1] + p.y + bv.y;
        tv.z = fa[q * 4 + 2] + p.z + bv.z;
        tv.w = fa[q * 4 + 3] + p.w + bv.w;
        const long o = row * 128 + 64 + m0;
        f32x4 ls = *(const f32x4*)(out + o);   // log_s stashed by s-phase (same thread)
        f32x4 z2 = *(const f32x4*)(z + o);
        f32x4 r;
        r.x = z2.x * __expf(ls.x) + tv.x;
        r.y = z2.y * __expf(ls.y) + tv.y;
        r.z = z2.z * __expf(ls.z) + tv.z;
        r.w = z2.w * __expf(ls.w) + tv.w;
        *(f32x4*)(out + o) = r;
      }
    }
  }
}

extern "C" void kernel_launch(void* const* d_in, const int* in_sizes, int n_in,
                              void* d_out, int out_size, void* d_ws, size_t ws_size,
                              hipStream_t stream) {
  const float* z     = (const float*)d_in[0];
  const float* sWin  = (const float*)d_in[1];
  const float* sbin  = (const float*)d_in[2];
  const float* sWhid = (const float*)d_in[3];
  const float* sbhid = (const float*)d_in[4];
  const float* sWout = (const float*)d_in[5];
  const float* sbout = (const float*)d_in[6];
  const float* tWin  = (const float*)d_in[7];
  const float* tbin  = (const float*)d_in[8];
  const float* tWhid = (const float*)d_in[9];
  const float* tbhid = (const float*)d_in[10];
  const float* tWout = (const float*)d_in[11];
  const float* tbout = (const float*)d_in[12];
  float* out = (float*)d_out;
  const size_t lds_bytes = 69632;   // 64KB k-major h + prefetch guard (2 blocks/CU)

  if (ws_size >= (size_t)W_ELEMS * sizeof(uint16_t)) {
    uint16_t* wbf = (uint16_t*)d_ws;
    cvt_weights<<<W_ELEMS / 4 / 256, 256, 0, stream>>>(sWin, sWhid, sWout, tWin, tWhid, tWout, wbf);
    coupling<true><<<NBLK, 512, lds_bytes, stream>>>(z, sWin, sbin, sWhid, sbhid, sWout, sbout,
                                                     tWin, tbin, tWhid, tbhid, tWout, tbout, wbf, out);
  } else {
    coupling<false><<<NBLK, 512, lds_bytes, stream>>>(z, sWin, sbin, sWhid, sbhid, sWout, sbout,
                                                      tWin, tbin, tWhid, tbhid, tWout, tbout,
                                                      (const uint16_t*)d_in[1], out);
  }
}

// Round 8
// 191.966 us; speedup vs baseline: 1.3059x; 1.1709x over previous
//
#include <hip/hip_runtime.h>
#include <stdint.h>

// AffineCoupling: B=65536 rows, DIM=128, D_IN=64, HID=512, 2 extra hidden layers.
// Fused bf16-MFMA, 32x32x16. 64 rows/block (1024 blocks), 8 waves, 2 blocks/CU
// (68KB LDS, launch_bounds(512,4): 128 unified regs/wave -> acc(64) in AGPR,
// ~50 arch VGPRs in-loop).
// Wave owns 64 neurons (nt=2) x 64 rows (rt=2): per K=16 step 2 A + 2 B loads
// feed 4 MFMAs; A and B double-buffered ONE step ahead with BOUNDED unroll
// windows (outer loops #pragma unroll 1) so the scheduler cannot hoist loads
// beyond the rotation -> no spill (R7 lesson: full unroll => 330MB scratch).
// Weights repacked k-major-tiled in d_ws: elem(m,k) -> (m>>5)*tsz + (k>>3)*256
// + (m&31)*8 + (k&7): an A-frag is ONE contiguous 1KB wave-load.
// LDS h k-major tiled: h[row][n] at byte (n>>3)*1024 + row*16 + (n&7)*2.
// Final (64-neuron) layers: k-split across 8 waves + LDS partial reduce.
// log_s stashed in out's z2 region between s- and t-MLP (same-thread RAW).

#define NROWS 65536
#define RPB   64
#define NBLK  (NROWS / RPB)

// bf16 weight scratch layout (element offsets in d_ws)
#define OFF_S_WIN   0
#define OFF_S_WHID  32768
#define OFF_S_WOUT  557056
#define OFF_T_WIN   589824
#define OFF_T_WHID  622592
#define OFF_T_WOUT  1146880
#define W_ELEMS     1179648

// LDS byte offsets (within per-block dynamic LDS, 69632 B total)
#define P_SCR  0        // final-layer partial tiles: 4 x 4352 B (reuses dead h)
#define SC2    17408    // log_det col-half sums: 128 x 4 B

typedef __attribute__((ext_vector_type(8)))  short short8;
typedef __attribute__((ext_vector_type(4)))  float f32x4;
typedef __attribute__((ext_vector_type(16))) float f32x16;

__device__ __forceinline__ uint32_t f2bf1(float f) {
  uint32_t u = __float_as_uint(f);
  return (u + 0x7fffu + ((u >> 16) & 1u)) >> 16;   // RNE
}
__device__ __forceinline__ uint32_t pk2bf(float a, float b) {
  return f2bf1(a) | (f2bf1(b) << 16);
}

// ---------------- weight fp32 -> bf16 + k-major repack prologue ----------------
__global__ void cvt_weights(const float* __restrict__ sWin, const float* __restrict__ sWhid,
                            const float* __restrict__ sWout, const float* __restrict__ tWin,
                            const float* __restrict__ tWhid, const float* __restrict__ tWout,
                            uint16_t* __restrict__ wbf) {
  int g = blockIdx.x * blockDim.x + threadIdx.x;
  int e = g * 4;
  if (e >= W_ELEMS) return;
  const float* src; int off, base; bool k64;
  if      (e < OFF_S_WHID) { src = sWin;  off = e;              base = OFF_S_WIN;  k64 = true; }
  else if (e < OFF_S_WOUT) { src = sWhid; off = e - OFF_S_WHID; base = OFF_S_WHID; k64 = false; }
  else if (e < OFF_T_WIN)  { src = sWout; off = e - OFF_S_WOUT; base = OFF_S_WOUT; k64 = false; }
  else if (e < OFF_T_WHID) { src = tWin;  off = e - OFF_T_WIN;  base = OFF_T_WIN;  k64 = true; }
  else if (e < OFF_T_WOUT) { src = tWhid; off = e - OFF_T_WHID; base = OFF_T_WHID; k64 = false; }
  else                     { src = tWout; off = e - OFF_T_WOUT; base = OFF_T_WOUT; k64 = false; }
  int m, k, tsz;
  if (k64) { m = off >> 6; k = off & 63;  tsz = 2048;  }
  else     { m = off >> 9; k = off & 511; tsz = 16384; }
  int dest = base + (m >> 5) * tsz + (k >> 3) * 256 + (m & 31) * 8 + (k & 7);
  f32x4 v = *(const f32x4*)(src + off);
  uint2 r; r.x = pk2bf(v.x, v.y); r.y = pk2bf(v.z, v.w);
  *(uint2*)(wbf + dest) = r;
}

// ---------------- A-frag loader ----------------
// packed idx = contiguous 1KB wave-load; orig idx only for the BF=false fallback.
template<bool BF>
__device__ __forceinline__ short8 ldW(const uint16_t* __restrict__ wb,
                                      const float* __restrict__ wf, int pidx, int oidx) {
  if (BF) {
    return *(const short8*)(wb + pidx);
  } else {
    f32x4 x = *(const f32x4*)(wf + oidx);
    f32x4 y = *(const f32x4*)(wf + oidx + 4);
    short8 r;
    r[0] = (short)f2bf1(x.x); r[1] = (short)f2bf1(x.y);
    r[2] = (short)f2bf1(x.z); r[3] = (short)f2bf1(x.w);
    r[4] = (short)f2bf1(y.x); r[5] = (short)f2bf1(y.y);
    r[6] = (short)f2bf1(y.z); r[7] = (short)f2bf1(y.w);
    return r;
  }
}

// ---------------- epilogue: bias + relu + pack + k-major LDS store ----------------
// C layout (32x32): col=lane&31=batch row; m=(reg&3)+8*(reg>>2)+4*(lane>>5).
__device__ __forceinline__ void store_h32(f32x16 acc[2][2], const float* __restrict__ bias,
                                          uint16_t* hdst, int wave, int lane) {
  const int l31 = lane & 31, lh = lane >> 5;
  __syncthreads();   // all waves done READING h (h is read+written in place)
  char* wp = (char*)hdst + wave * 8192 + l31 * 16 + lh * 8;
  #pragma unroll
  for (int nt = 0; nt < 2; ++nt) {
    #pragma unroll
    for (int q = 0; q < 4; ++q) {
      const int m0 = wave * 64 + nt * 32 + q * 8 + lh * 4;
      f32x4 bv = *(const f32x4*)(bias + m0);
      #pragma unroll
      for (int rt = 0; rt < 2; ++rt) {
        float v0 = acc[nt][rt][q * 4 + 0] + bv.x;
        float v1 = acc[nt][rt][q * 4 + 1] + bv.y;
        float v2 = acc[nt][rt][q * 4 + 2] + bv.z;
        float v3 = acc[nt][rt][q * 4 + 3] + bv.w;
        uint2 p;
        p.x = pk2bf(fmaxf(v0, 0.f), fmaxf(v1, 0.f));
        p.y = pk2bf(fmaxf(v2, 0.f), fmaxf(v3, 0.f));
        *(uint2*)(wp + nt * 4096 + q * 1024 + rt * 512) = p;
      }
    }
  }
  __syncthreads();
}

// ---------------- layer 1: h = relu(W @ z1^T + b), K=64, B built from global z ----------------
template<bool BF>
__device__ __forceinline__ void dense_in(
    const uint16_t* __restrict__ wb, const float* __restrict__ wf,
    const float* __restrict__ bias, const float* __restrict__ z, long rowbase,
    uint16_t* hdst, int wave, int lane) {
  const int l31 = lane & 31, lh = lane >> 5;
  f32x16 acc[2][2];
  #pragma unroll
  for (int i = 0; i < 2; ++i)
    #pragma unroll
    for (int j = 0; j < 2; ++j) acc[i][j] = (f32x16)0.f;
  #pragma unroll 1
  for (int ks = 0; ks < 4; ++ks) {
    short8 a[2];
    #pragma unroll
    for (int nt = 0; nt < 2; ++nt)
      a[nt] = ldW<BF>(wb, wf,
                      (wave * 2 + nt) * 2048 + (2 * ks + lh) * 256 + l31 * 8,
                      (wave * 64 + nt * 32 + l31) * 64 + ks * 16 + lh * 8);
    #pragma unroll
    for (int rt = 0; rt < 2; ++rt) {
      const float* zp = z + (rowbase + rt * 32 + l31) * 128 + ks * 16 + lh * 8;
      f32x4 u = *(const f32x4*)zp;
      f32x4 v = *(const f32x4*)(zp + 4);
      short8 b;
      b[0] = (short)f2bf1(u.x); b[1] = (short)f2bf1(u.y);
      b[2] = (short)f2bf1(u.z); b[3] = (short)f2bf1(u.w);
      b[4] = (short)f2bf1(v.x); b[5] = (short)f2bf1(v.y);
      b[6] = (short)f2bf1(v.z); b[7] = (short)f2bf1(v.w);
      #pragma unroll
      for (int nt = 0; nt < 2; ++nt)
        acc[nt][rt] = __builtin_amdgcn_mfma_f32_32x32x16_bf16(a[nt], b, acc[nt][rt], 0, 0, 0);
    }
  }
  store_h32(acc, bias, hdst, wave, lane);
}

// ---------------- hidden layer: h = relu(W @ h^T + b), K=512 ----------------
// 32 K=16 steps as 8 chunks x 4; A and B double-buffered one step ahead.
// Outer loop NOT unrolled -> scheduler hoisting window bounded to the chunk.
template<bool BF>
__device__ __forceinline__ void dense_relu512(
    const uint16_t* __restrict__ wb, const float* __restrict__ wf,
    const float* __restrict__ bias, uint16_t* hbuf, int wave, int lane) {
  const int l31 = lane & 31, lh = lane >> 5;
  f32x16 acc[2][2];
  #pragma unroll
  for (int i = 0; i < 2; ++i)
    #pragma unroll
    for (int j = 0; j < 2; ++j) acc[i][j] = (f32x16)0.f;
  const int wbaseP = wave * 2 * 16384 + lh * 256 + l31 * 8;   // + nt*16384 + ks*512
  const int wbaseO = (wave * 64 + l31) * 512 + lh * 8;        // + nt*32*512 + ks*16
  const char* bb = (const char*)hbuf + l31 * 16 + lh * 1024;  // + ks*2048 + rt*512

  short8 aA[2], aB[2], bA[2], bB[2];
  aA[0] = ldW<BF>(wb, wf, wbaseP, wbaseO);
  aA[1] = ldW<BF>(wb, wf, wbaseP + 16384, wbaseO + 16384);
  bA[0] = *(const short8*)(bb);
  bA[1] = *(const short8*)(bb + 512);

  #pragma unroll 1
  for (int c = 0; c < 8; ++c) {
    const char* bc = bb + c * 8192;
    const int kc = c * 4;
    #pragma unroll
    for (int j = 0; j < 4; ++j) {
      const int ks = kc + j;
      const int kp = (ks + 1 > 31) ? 31 : (ks + 1);   // A clamp (harmless re-read)
      aB[0] = ldW<BF>(wb, wf, wbaseP + kp * 512,         wbaseO + kp * 16);
      aB[1] = ldW<BF>(wb, wf, wbaseP + 16384 + kp * 512, wbaseO + 16384 + kp * 16);
      bB[0] = *(const short8*)(bc + (j + 1) * 2048);          // ks=31 -> guard region
      bB[1] = *(const short8*)(bc + (j + 1) * 2048 + 512);
      __builtin_amdgcn_s_setprio(1);
      acc[0][0] = __builtin_amdgcn_mfma_f32_32x32x16_bf16(aA[0], bA[0], acc[0][0], 0, 0, 0);
      acc[0][1] = __builtin_amdgcn_mfma_f32_32x32x16_bf16(aA[0], bA[1], acc[0][1], 0, 0, 0);
      acc[1][0] = __builtin_amdgcn_mfma_f32_32x32x16_bf16(aA[1], bA[0], acc[1][0], 0, 0, 0);
      acc[1][1] = __builtin_amdgcn_mfma_f32_32x32x16_bf16(aA[1], bA[1], acc[1][1], 0, 0, 0);
      __builtin_amdgcn_s_setprio(0);
      aA[0] = aB[0]; aA[1] = aB[1];
      bA[0] = bB[0]; bA[1] = bB[1];
    }
  }
  store_h32(acc, bias, hbuf, wave, lane);
}

// ---------------- final layer partial: 64 neurons, k-split across 8 waves ----------------
// wave w: nt=w&1 (32 neurons), rt=(w>>1)&1 (32 rows), kh=w>>2 (k half).
// Chunked 4x4 so at most 4 steps' loads are in flight.
template<bool BF>
__device__ __forceinline__ void final_partial(
    const uint16_t* __restrict__ wb, const float* __restrict__ wf,
    const uint16_t* hbuf, int nt, int rt, int kh, int lane, f32x16& acc) {
  const int l31 = lane & 31, lh = lane >> 5;
  acc = (f32x16)0.f;
  #pragma unroll 1
  for (int c = 0; c < 4; ++c) {
    #pragma unroll
    for (int j = 0; j < 4; ++j) {
      const int ks = c * 4 + j;
      const int kt = 2 * (kh * 16 + ks) + lh;
      short8 a = ldW<BF>(wb, wf, nt * 16384 + kt * 256 + l31 * 8,
                         (nt * 32 + l31) * 512 + kh * 256 + ks * 16 + lh * 8);
      short8 b = *(const short8*)((const char*)hbuf + kt * 1024 + (rt * 32 + l31) * 16);
      acc = __builtin_amdgcn_mfma_f32_32x32x16_bf16(a, b, acc, 0, 0, 0);
    }
  }
}

// ---------------- fused coupling kernel: 64 rows/block, 8 waves, 2 blocks/CU ----------------
template<bool BF>
__global__ __launch_bounds__(512, 4) void coupling(
    const float* __restrict__ z,
    const float* __restrict__ sWin, const float* __restrict__ sbin,
    const float* __restrict__ sWhid, const float* __restrict__ sbhid,
    const float* __restrict__ sWout, const float* __restrict__ sbout,
    const float* __restrict__ tWin, const float* __restrict__ tbin,
    const float* __restrict__ tWhid, const float* __restrict__ tbhid,
    const float* __restrict__ tWout, const float* __restrict__ tbout,
    const uint16_t* __restrict__ wbf, float* __restrict__ out) {
  extern __shared__ __align__(16) uint16_t h[];     // 64KB k-major h + guard
  const int tid = threadIdx.x;
  const int wave = tid >> 6, lane = tid & 63;
  const int l31 = lane & 31, lh = lane >> 5;
  const long rowbase = (long)blockIdx.x * RPB;
  const int fnt = wave & 1, frt = (wave >> 1) & 1, fkh = wave >> 2;

  // ---------------- s MLP ----------------
  dense_in<BF>(wbf + OFF_S_WIN, sWin, sbin, z, rowbase, h, wave, lane);
  dense_relu512<BF>(wbf + OFF_S_WHID, sWhid, sbhid, h, wave, lane);
  dense_relu512<BF>(wbf + OFF_S_WHID + 262144, sWhid + 262144, sbhid + 512, h, wave, lane);

  // z1 passthrough copy (all waves; independent of h)
  #pragma unroll
  for (int i = 0; i < 2; ++i) {
    int v = tid + i * 512;
    int row = v >> 4, kc = (v & 15) * 4;
    *(f32x4*)(out + (rowbase + row) * 128 + kc) =
        *(const f32x4*)(z + (rowbase + row) * 128 + kc);
  }

  // ---- s final: k-split partials + LDS reduce + clip/stash/logdet ----
  {
    f32x16 fa;
    final_partial<BF>(wbf + OFF_S_WOUT, sWout, h, fnt, frt, fkh, lane, fa);
    __syncthreads();                 // all reads of h done; scratch area reusable
    char* sc = (char*)h + P_SCR + (fnt * 2 + frt) * 4352 + lane * 68;
    if (fkh) {
      #pragma unroll
      for (int q = 0; q < 4; ++q)
        *(f32x4*)(sc + q * 16) = (f32x4){fa[q * 4], fa[q * 4 + 1], fa[q * 4 + 2], fa[q * 4 + 3]};
    }
    __syncthreads();
    if (!fkh) {
      const long row = rowbase + frt * 32 + l31;
      float sum = 0.f;
      #pragma unroll
      for (int q = 0; q < 4; ++q) {
        f32x4 p = *(const f32x4*)(sc + q * 16);
        const int m0 = fnt * 32 + q * 8 + lh * 4;
        f32x4 bv = *(const f32x4*)(sbout + m0);
        f32x4 v;
        v.x = fminf(fmaxf(fa[q * 4 + 0] + p.x + bv.x, -2.f), 2.f);
        v.y = fminf(fmaxf(fa[q * 4 + 1] + p.y + bv.y, -2.f), 2.f);
        v.z = fminf(fmaxf(fa[q * 4 + 2] + p.z + bv.z, -2.f), 2.f);
        v.w = fminf(fmaxf(fa[q * 4 + 3] + p.w + bv.w, -2.f), 2.f);
        sum += v.x + v.y + v.z + v.w;
        *(f32x4*)(out + row * 128 + 64 + m0) = v;   // stash log_s
      }
      sum += __shfl_xor(sum, 32, 64);               // combine lh col-halves
      if (lane < 32)
        *(float*)((char*)h + SC2 + (fnt * 64 + frt * 32 + l31) * 4) = sum;
    }
    __syncthreads();
    if ((wave == 0 || wave == 2) && lane < 32) {    // nt=0, kh=0 waves finish log_det
      float t0 = *(const float*)((char*)h + SC2 + (frt * 32 + l31) * 4);
      float t1 = *(const float*)((char*)h + SC2 + (64 + frt * 32 + l31) * 4);
      out[(long)NROWS * 128 + rowbase + frt * 32 + l31] = t0 + t1;
    }
  }
  __syncthreads();

  // ---------------- t MLP ----------------
  dense_in<BF>(wbf + OFF_T_WIN, tWin, tbin, z, rowbase, h, wave, lane);
  dense_relu512<BF>(wbf + OFF_T_WHID, tWhid, tbhid, h, wave, lane);
  dense_relu512<BF>(wbf + OFF_T_WHID + 262144, tWhid + 262144, tbhid + 512, h, wave, lane);

  // ---- t final: k-split partials + LDS reduce + z2 combine ----
  {
    f32x16 fa;
    final_partial<BF>(wbf + OFF_T_WOUT, tWout, h, fnt, frt, fkh, lane, fa);
    __syncthreads();
    char* sc = (char*)h + P_SCR + (fnt * 2 + frt) * 4352 + lane * 68;
    if (fkh) {
      #pragma unroll
      for (int q = 0; q < 4; ++q)
        *(f32x4*)(sc + q * 16) = (f32x4){fa[q * 4], fa[q * 4 + 1], fa[q * 4 + 2], fa[q * 4 + 3]};
    }
    __syncthreads();
    if (!fkh) {
      const long row = rowbase + frt * 32 + l31;
      #pragma unroll
      for (int q = 0; q < 4; ++q) {
        f32x4 p = *(const f32x4*)(sc + q * 16);
        const int m0 = fnt * 32 + q * 8 + lh * 4;
        f32x4 bv = *(const f32x4*)(tbout + m0);
        f32x4 tv;
        tv.x = fa[q * 4 + 0] + p.x + bv.x;
        tv.y = fa[q * 4 + 1] + p.y + bv.y;
        tv.z = fa[q * 4 + 2] + p.z + bv.z;
        tv.w = fa[q * 4 + 3] + p.w + bv.w;
        const long o = row * 128 + 64 + m0;
        f32x4 ls = *(const f32x4*)(out + o);   // log_s stashed by s-phase (same thread)
        f32x4 z2 = *(const f32x4*)(z + o);
        f32x4 r;
        r.x = z2.x * __expf(ls.x) + tv.x;
        r.y = z2.y * __expf(ls.y) + tv.y;
        r.z = z2.z * __expf(ls.z) + tv.z;
        r.w = z2.w * __expf(ls.w) + tv.w;
        *(f32x4*)(out + o) = r;
      }
    }
  }
}

extern "C" void kernel_launch(void* const* d_in, const int* in_sizes, int n_in,
                              void* d_out, int out_size, void* d_ws, size_t ws_size,
                              hipStream_t stream) {
  const float* z     = (const float*)d_in[0];
  const float* sWin  = (const float*)d_in[1];
  const float* sbin  = (const float*)d_in[2];
  const float* sWhid = (const float*)d_in[3];
  const float* sbhid = (const float*)d_in[4];
  const float* sWout = (const float*)d_in[5];
  const float* sbout = (const float*)d_in[6];
  const float* tWin  = (const float*)d_in[7];
  const float* tbin  = (const float*)d_in[8];
  const float* tWhid = (const float*)d_in[9];
  const float* tbhid = (const float*)d_in[10];
  const float* tWout = (const float*)d_in[11];
  const float* tbout = (const float*)d_in[12];
  float* out = (float*)d_out;
  const size_t lds_bytes = 69632;   // 64KB k-major h + prefetch guard (2 blocks/CU)

  if (ws_size >= (size_t)W_ELEMS * sizeof(uint16_t)) {
    uint16_t* wbf = (uint16_t*)d_ws;
    cvt_weights<<<W_ELEMS / 4 / 256, 256, 0, stream>>>(sWin, sWhid, sWout, tWin, tWhid, tWout, wbf);
    coupling<true><<<NBLK, 512, lds_bytes, stream>>>(z, sWin, sbin, sWhid, sbhid, sWout, sbout,
                                                     tWin, tbin, tWhid, tbhid, tWout, tbout, wbf, out);
  } else {
    coupling<false><<<NBLK, 512, lds_bytes, stream>>>(z, sWin, sbin, sWhid, sbhid, sWout, sbout,
                                                      tWin, tbin, tWhid, tbhid, tWout, tbout,
                                                      (const uint16_t*)d_in[1], out);
  }
}